// Round 9
// baseline (257.614 us; speedup 1.0000x reference)
//
#include <hip/hip_runtime.h>
#include <float.h>
#include <math.h>

#define SEQ 2048
#define NB 4
#define DIM 128
#define DL 16
#define NEGV (-1e9f)
#define TOPK 8

#define QT 128      // q-rows per out block
#define KC 64       // k chunk staged in LDS (out kernel)

typedef unsigned long long u64;
typedef __attribute__((ext_vector_type(8))) short short8;
typedef __attribute__((ext_vector_type(4))) float f32x4;

__device__ __forceinline__ int lanes_below(u64 m) {
    return __builtin_amdgcn_mbcnt_hi((unsigned)(m >> 32),
           __builtin_amdgcn_mbcnt_lo((unsigned)m, 0));
}

__device__ __forceinline__ void top8_insert(float* s, float key) {
    #pragma unroll
    for (int i = 0; i < 8; ++i) {
        float a = s[i];
        s[i] = fmaxf(a, key);
        key  = fminf(a, key);
    }
}

__device__ __forceinline__ float top8_merge(float* s) {
    #pragma unroll
    for (int off = 1; off < 64; off <<= 1) {
        float o[8], t[8];
        #pragma unroll
        for (int i = 0; i < 8; ++i)
            o[i] = __shfl_xor(s[i], off, 64);
        #pragma unroll
        for (int i = 0; i < 8; ++i)
            t[i] = fmaxf(s[i], o[7 - i]);
        #pragma unroll
        for (int i = 0; i < 4; ++i) {
            float a = t[i], c = t[i + 4];
            t[i] = fmaxf(a, c); t[i + 4] = fminf(a, c);
        }
        #pragma unroll
        for (int g2 = 0; g2 < 8; g2 += 4) {
            float a = t[g2], c = t[g2 + 2];
            t[g2] = fmaxf(a, c); t[g2 + 2] = fminf(a, c);
            a = t[g2 + 1]; c = t[g2 + 3];
            t[g2 + 1] = fmaxf(a, c); t[g2 + 3] = fminf(a, c);
        }
        #pragma unroll
        for (int g1 = 0; g1 < 8; g1 += 2) {
            float a = t[g1], c = t[g1 + 1];
            t[g1] = fmaxf(a, c); t[g1 + 1] = fminf(a, c);
        }
        #pragma unroll
        for (int i = 0; i < 8; ++i) s[i] = t[i];
    }
    return s[7];
}

// bf16 round-to-nearest-even of f32 (returns 16-bit pattern)
__device__ __forceinline__ unsigned bf16_rne(float x) {
    unsigned u = __float_as_uint(x);
    return (u + 0x7FFFu + ((u >> 16) & 1u)) >> 16;
}

// ---------------------------------------------------------------------------
// Kernel A: q_low/k_low projections + per-key high-rank correction scalar sh.
// ---------------------------------------------------------------------------
__global__ __launch_bounds__(256) void proj_kernel(
    const float* __restrict__ q, const float* __restrict__ k,
    const float* __restrict__ Wql, const float* __restrict__ bql,
    const float* __restrict__ Wkl, const float* __restrict__ bkl,
    const float* __restrict__ Wqh, const float* __restrict__ bqh,
    const float* __restrict__ Wkh, const float* __restrict__ bkh,
    float* __restrict__ q_low, float* __restrict__ k_low,
    float* __restrict__ sh)
{
    __shared__ float Ws[4][DIM * DL];
    __shared__ float rowq[16][DIM];
    __shared__ float rowk[16][DIM];
    int tid = threadIdx.x;
    for (int i = tid; i < DIM * DL; i += 256) {
        Ws[0][i] = Wql[i];
        Ws[1][i] = Wkl[i];
        Ws[2][i] = Wqh[i];
        Ws[3][i] = Wkh[i];
    }
    int r0 = blockIdx.x * 16;
    for (int i = tid; i < 16 * DIM; i += 256) {
        int rr = i >> 7, cc = i & 127;
        rowq[rr][cc] = q[(size_t)(r0 + rr) * DIM + cc];
        rowk[rr][cc] = k[(size_t)(r0 + rr) * DIM + cc];
    }
    __syncthreads();
    int g = tid >> 4;
    int e = tid & 15;
    float aql = 0.f, akl = 0.f, aqh = 0.f, akh = 0.f;
    #pragma unroll 8
    for (int i = 0; i < DIM; ++i) {
        float qv = rowq[g][i], kv = rowk[g][i];
        aql = fmaf(qv, Ws[0][i * DL + e], aql);
        akl = fmaf(kv, Ws[1][i * DL + e], akl);
        aqh = fmaf(qv, Ws[2][i * DL + e], aqh);
        akh = fmaf(kv, Ws[3][i * DL + e], akh);
    }
    int t = r0 + g;
    q_low[(size_t)t * DL + e] = aql + bql[e];
    k_low[(size_t)t * DL + e] = akl + bkl[e];
    float qp = aqh + bqh[e];
    float kp = akh + bkh[e];
    float prod = qp * kp;
    #pragma unroll
    for (int off = 8; off >= 1; off >>= 1)
        prod += __shfl_xor(prod, off, 16);
    if (e == 0) sh[t] = 0.25f * prod;
}

// ---------------------------------------------------------------------------
// Kernel A2: V transpose + bf16 hi/lo split: VthH/VthL[b][d][k].
// ---------------------------------------------------------------------------
__global__ __launch_bounds__(256) void vsplit_kernel(
    const float* __restrict__ V, unsigned short* __restrict__ VH,
    unsigned short* __restrict__ VL)
{
    __shared__ float T[32][33];
    int kb = blockIdx.x * 32, db = blockIdx.y * 32, b = blockIdx.z;
    int tid = threadIdx.x;
    {
        int r = tid >> 3, cg = tid & 7;
        float4 v = *(const float4*)(V + ((size_t)b * SEQ + kb + r) * DIM + db + cg * 4);
        T[r][cg * 4 + 0] = v.x; T[r][cg * 4 + 1] = v.y;
        T[r][cg * 4 + 2] = v.z; T[r][cg * 4 + 3] = v.w;
    }
    __syncthreads();
    int dr = tid >> 3, kg = tid & 7;
    unsigned h[4], l[4];
    #pragma unroll
    for (int j = 0; j < 4; ++j) {
        float f = T[kg * 4 + j][dr];
        unsigned hi = bf16_rne(f);
        float hf = __uint_as_float(hi << 16);
        unsigned lo = bf16_rne(f - hf);
        h[j] = hi; l[j] = lo;
    }
    size_t o = ((size_t)b * DIM + db + dr) * SEQ + kb + kg * 4;
    *(uint2*)(VH + o) = make_uint2(h[0] | (h[1] << 16), h[2] | (h[3] << 16));
    *(uint2*)(VL + o) = make_uint2(l[0] | (l[1] << 16), l[2] | (l[3] << 16));
}

// ---------------------------------------------------------------------------
// Kernel B v8: R6's score_topk5 (best measured: 60.7 us) + fused column
// exp-sum. Block = 4 waves x 2 rows. k_low via 2-buffer LDS pipeline
// (col-major stride 16). Pass 1: scores -> Smat + value-only top-8.
// Pass 2: patch 8 winners with sh (exact ties) AND accumulate
// exp(patched) into LDS colsum[2048]; block partial -> pcol.
// ---------------------------------------------------------------------------
__global__ __launch_bounds__(256) void score_topk8(
    const float* __restrict__ q_low, const float* __restrict__ k_low,
    const float* __restrict__ sh, const int* __restrict__ valid_lens,
    float* __restrict__ Smat, float* __restrict__ pcol)
{
    __shared__ float KT[2][256 * DL];   // 2 x 16 KB
    __shared__ float colsum[SEQ];       // 8 KB

    int tid  = threadIdx.x;
    int lane = tid & 63;
    int wv   = tid >> 6;
    int row0 = __builtin_amdgcn_readfirstlane(blockIdx.x * 8 + wv * 2);
    int b    = row0 >> 11;
    int qi0  = row0 & (SEQ - 1);
    int qi1  = qi0 + 1;

    float qv0[16], qv1[16];
    {
        const float* qp0 = q_low + (size_t)row0 * DL;
        #pragma unroll
        for (int e = 0; e < 16; ++e) { qv0[e] = qp0[e]; qv1[e] = qp0[DL + e]; }
    }

    const float4* kb4 = (const float4*)(k_low + (size_t)b * SEQ * DL);
    const int*    vlb = valid_lens + (size_t)b * SEQ;
    const float*  shb = sh + (size_t)b * SEQ;
    float* Srow0 = Smat + (size_t)row0 * SEQ;
    float* Srow1 = Srow0 + SEQ;

    float s0[8], s1[8];
    #pragma unroll
    for (int i = 0; i < 8; ++i) { s0[i] = -FLT_MAX; s1[i] = -FLT_MAX; }

    // zero colsum (covered by the prologue barrier)
    #pragma unroll
    for (int i = 0; i < 8; ++i) colsum[tid + i * 256] = 0.f;

    float4 stg[4];
    #pragma unroll
    for (int i = 0; i < 4; ++i) stg[i] = kb4[tid + i * 256];
    {
        float4* d = (float4*)KT[0];
        #pragma unroll
        for (int i = 0; i < 4; ++i) d[tid + i * 256] = stg[i];
    }
    __syncthreads();

    for (int c = 0; c < 8; ++c) {
        if (c < 7) {
            #pragma unroll
            for (int i = 0; i < 4; ++i)
                stg[i] = kb4[(c + 1) * 1024 + tid + i * 256];
        }
        int vli[4];
        #pragma unroll
        for (int j = 0; j < 4; ++j)
            vli[j] = vlb[c * 256 + lane + j * 64];

        const float* Kc = KT[c & 1];
        #pragma unroll
        for (int j = 0; j < 4; ++j) {
            int ccol = lane + j * 64;
            int col  = c * 256 + ccol;
            const float4* kp4 = (const float4*)(Kc + ccol * DL);
            float4 v0 = kp4[0], v1 = kp4[1], v2 = kp4[2], v3 = kp4[3];

            float a0 = 0.f, a1 = 0.f;
            a0 = fmaf(qv0[0],  v0.x, a0); a1 = fmaf(qv1[0],  v0.x, a1);
            a0 = fmaf(qv0[1],  v0.y, a0); a1 = fmaf(qv1[1],  v0.y, a1);
            a0 = fmaf(qv0[2],  v0.z, a0); a1 = fmaf(qv1[2],  v0.z, a1);
            a0 = fmaf(qv0[3],  v0.w, a0); a1 = fmaf(qv1[3],  v0.w, a1);
            a0 = fmaf(qv0[4],  v1.x, a0); a1 = fmaf(qv1[4],  v1.x, a1);
            a0 = fmaf(qv0[5],  v1.y, a0); a1 = fmaf(qv1[5],  v1.y, a1);
            a0 = fmaf(qv0[6],  v1.z, a0); a1 = fmaf(qv1[6],  v1.z, a1);
            a0 = fmaf(qv0[7],  v1.w, a0); a1 = fmaf(qv1[7],  v1.w, a1);
            a0 = fmaf(qv0[8],  v2.x, a0); a1 = fmaf(qv1[8],  v2.x, a1);
            a0 = fmaf(qv0[9],  v2.y, a0); a1 = fmaf(qv1[9],  v2.y, a1);
            a0 = fmaf(qv0[10], v2.z, a0); a1 = fmaf(qv1[10], v2.z, a1);
            a0 = fmaf(qv0[11], v2.w, a0); a1 = fmaf(qv1[11], v2.w, a1);
            a0 = fmaf(qv0[12], v3.x, a0); a1 = fmaf(qv1[12], v3.x, a1);
            a0 = fmaf(qv0[13], v3.y, a0); a1 = fmaf(qv1[13], v3.y, a1);
            a0 = fmaf(qv0[14], v3.z, a0); a1 = fmaf(qv1[14], v3.z, a1);
            a0 = fmaf(qv0[15], v3.w, a0); a1 = fmaf(qv1[15], v3.w, a1);
            a0 *= 0.25f; a1 *= 0.25f;

            int v = vli[j];
            v = v < 0 ? 0 : (v > SEQ - 1 ? SEQ - 1 : v);
            if (v == qi0) a0 += NEGV;
            if (v == qi1) a1 += NEGV;
            Srow0[col] = a0;
            Srow1[col] = a1;
            top8_insert(s0, a0);
            top8_insert(s1, a1);
        }
        if (c < 7) {
            float* d = KT[(c + 1) & 1];
            #pragma unroll
            for (int i = 0; i < 4; ++i)
                *((float4*)d + tid + i * 256) = stg[i];
            __syncthreads();
        }
    }

    float t8[2];
    t8[0] = top8_merge(s0);
    t8[1] = top8_merge(s1);

    // pass 2: patch winners with sh; accumulate exp(patched) into colsum
    for (int r = 0; r < 2; ++r) {
        float* Sr = r ? Srow1 : Srow0;
        float thr = t8[r];
        float sc[32];
        #pragma unroll 8
        for (int j = 0; j < 32; ++j)
            sc[j] = Sr[lane + j * 64];
        int cnt = 0;
        #pragma unroll
        for (int j = 0; j < 32; ++j) {
            cnt += (sc[j] >= thr) ? 1 : 0;
            cnt += (sc[j] >  thr) ? 65536 : 0;
        }
        #pragma unroll
        for (int off = 1; off < 64; off <<= 1)
            cnt += __shfl_xor(cnt, off, 64);
        int c_ge = cnt & 0xFFFF;
        int c_gt = cnt >> 16;

        if (c_ge == 8) {
            #pragma unroll 8
            for (int j = 0; j < 32; ++j) {
                int col = lane + j * 64;
                bool sel = (sc[j] >= thr);
                float v = sel ? shb[col] : sc[j];
                if (sel) Sr[col] = v;
                atomicAdd(&colsum[col], __expf(v));
            }
        } else {
            int need = 8 - c_gt;
            int total = 0;
            for (int j = 0; j < 32; ++j) {
                int col = lane + j * 64;
                bool eq = (sc[j] == thr);
                u64 bal = __ballot(eq);
                int before = total + lanes_below(bal);
                bool sel = (sc[j] > thr) || (eq && before < need);
                float v = sel ? shb[col] : sc[j];
                if (sel) Sr[col] = v;
                atomicAdd(&colsum[col], __expf(v));
                total += (int)__popcll(bal);
            }
        }
    }

    __syncthreads();
    float* pc = pcol + (size_t)blockIdx.x * SEQ;
    #pragma unroll
    for (int i = 0; i < 8; ++i)
        pc[tid + i * 256] = colsum[tid + i * 256];
}

// ---------------------------------------------------------------------------
// Kernel C: reduce block partials (256 per batch) -> cinv[b][k].
// ---------------------------------------------------------------------------
__global__ __launch_bounds__(256) void colred_final2(
    const float* __restrict__ pcol, float* __restrict__ cinv)
{
    int idx = blockIdx.x * 256 + threadIdx.x;   // 0..8191
    int b = idx >> 11, kcol = idx & (SEQ - 1);
    const float* p = pcol + (size_t)b * 256 * SEQ + kcol;
    float l = 0.f;
    #pragma unroll 8
    for (int c = 0; c < 256; ++c)
        l += p[(size_t)c * SEQ];
    cinv[idx] = 1.f / l;
}

// ---------------------------------------------------------------------------
// Kernel D v3: MFMA PV. Block = 128q x 128d, k-chunks of 64, ksplit partials.
// P A-fragments in registers from global S (hi/lo bf16 split); V^T hi/lo in
// XOR-swizzled LDS. out = PhVh + PlVh + PhVl.
// ---------------------------------------------------------------------------
__global__ __launch_bounds__(256) void out_mfma(
    const float* __restrict__ Smat, const unsigned short* __restrict__ VH,
    const unsigned short* __restrict__ VL,
    const float* __restrict__ cinv,
    float* __restrict__ dst, int krange)
{
    __shared__ unsigned int VtH[DIM * 32];   // 16 KB
    __shared__ unsigned int VtL[DIM * 32];   // 16 KB

    int tid  = threadIdx.x;
    int w    = tid >> 6;
    int lane = tid & 63;
    int ln   = lane & 15;
    int quad = lane >> 4;
    int q0   = blockIdx.x * QT;
    int ksid = blockIdx.y;
    int b    = blockIdx.z;
    int kbeg = ksid * krange;

    const float* Sb = Smat + (size_t)b * SEQ * SEQ;
    const unsigned short* VHb = VH + (size_t)b * DIM * SEQ;
    const unsigned short* VLb = VL + (size_t)b * DIM * SEQ;
    const float* ci = cinv + (size_t)b * SEQ;

    f32x4 acc[2][8];
    #pragma unroll
    for (int mt = 0; mt < 2; ++mt)
        #pragma unroll
        for (int nt = 0; nt < 8; ++nt)
            acc[mt][nt] = (f32x4){0.f, 0.f, 0.f, 0.f};

    int sd0   = tid >> 3;
    int skseg = tid & 7;

    for (int k0 = kbeg; k0 < kbeg + krange; k0 += KC) {
        #pragma unroll
        for (int it = 0; it < 4; ++it) {
            int d = sd0 + it * 32;
            size_t go = (size_t)d * SEQ + k0 + skseg * 8;
            uint4 hv = *(const uint4*)(VHb + go);
            uint4 lv = *(const uint4*)(VLb + go);
            int wa = d * 32 + ((skseg ^ (d & 7)) << 2);
            *(uint4*)&VtH[wa] = hv;
            *(uint4*)&VtL[wa] = lv;
        }

        short8 Ah[2][2], Al[2][2];
        #pragma unroll
        for (int ks = 0; ks < 2; ++ks) {
            int kk = k0 + ks * 32 + quad * 8;
            float4 cia = *(const float4*)(ci + kk);
            float4 cib = *(const float4*)(ci + kk + 4);
            #pragma unroll
            for (int mt = 0; mt < 2; ++mt) {
                const float* Sp = Sb + (size_t)(q0 + w * 32 + mt * 16 + ln) * SEQ + kk;
                float4 sa = *(const float4*)Sp;
                float4 sb = *(const float4*)(Sp + 4);
                float p[8];
                p[0] = __expf(sa.x) * cia.x;
                p[1] = __expf(sa.y) * cia.y;
                p[2] = __expf(sa.z) * cia.z;
                p[3] = __expf(sa.w) * cia.w;
                p[4] = __expf(sb.x) * cib.x;
                p[5] = __expf(sb.y) * cib.y;
                p[6] = __expf(sb.z) * cib.z;
                p[7] = __expf(sb.w) * cib.w;
                #pragma unroll
                for (int j = 0; j < 8; ++j) {
                    unsigned hi = bf16_rne(p[j]);
                    float hf = __uint_as_float(hi << 16);
                    unsigned lo = bf16_rne(p[j] - hf);
                    Ah[mt][ks][j] = (short)hi;
                    Al[mt][ks][j] = (short)lo;
                }
            }
        }
        __syncthreads();

        #pragma unroll
        for (int nt = 0; nt < 8; ++nt) {
            int d = nt * 16 + ln;
            #pragma unroll
            for (int ks = 0; ks < 2; ++ks) {
                int kseg = ks * 4 + quad;
                int wa = d * 32 + ((kseg ^ (d & 7)) << 2);
                short8 bh = *(short8*)&VtH[wa];
                short8 bl = *(short8*)&VtL[wa];
                #pragma unroll
                for (int mt = 0; mt < 2; ++mt) {
                    acc[mt][nt] = __builtin_amdgcn_mfma_f32_16x16x32_bf16(
                        Ah[mt][ks], bh, acc[mt][nt], 0, 0, 0);
                    acc[mt][nt] = __builtin_amdgcn_mfma_f32_16x16x32_bf16(
                        Al[mt][ks], bh, acc[mt][nt], 0, 0, 0);
                    acc[mt][nt] = __builtin_amdgcn_mfma_f32_16x16x32_bf16(
                        Ah[mt][ks], bl, acc[mt][nt], 0, 0, 0);
                }
            }
        }
        __syncthreads();
    }

    float* dp = dst + (size_t)ksid * ((size_t)NB * SEQ * DIM)
                    + (size_t)b * SEQ * DIM;
    #pragma unroll
    for (int mt = 0; mt < 2; ++mt) {
        #pragma unroll
        for (int r = 0; r < 4; ++r) {
            float* o = dp + (size_t)(q0 + w * 32 + mt * 16 + quad * 4 + r) * DIM + ln;
            #pragma unroll
            for (int nt = 0; nt < 8; ++nt)
                o[nt * 16] = acc[mt][nt][r];
        }
    }
}

__global__ __launch_bounds__(256) void reduce_kernel(
    const float* __restrict__ part, float* __restrict__ out, int ksplit)
{
    int idx = blockIdx.x * 256 + threadIdx.x;
    const float4* p = (const float4*)part;
    float4 a = p[idx];
    for (int s = 1; s < ksplit; ++s) {
        float4 q = p[(size_t)idx + (size_t)s * 262144];
        a.x += q.x; a.y += q.y; a.z += q.z; a.w += q.w;
    }
    ((float4*)out)[idx] = a;
}

extern "C" void kernel_launch(void* const* d_in, const int* in_sizes, int n_in,
                              void* d_out, int out_size, void* d_ws, size_t ws_size,
                              hipStream_t stream)
{
    const float* queries = (const float*)d_in[0];
    const float* keys    = (const float*)d_in[1];
    const float* values  = (const float*)d_in[2];
    const int*   valid   = (const int*)d_in[3];
    const float* Wql = (const float*)d_in[4];
    const float* bql = (const float*)d_in[5];
    const float* Wkl = (const float*)d_in[6];
    const float* bkl = (const float*)d_in[7];
    const float* Wqh = (const float*)d_in[8];
    const float* bqh = (const float*)d_in[9];
    const float* Wkh = (const float*)d_in[10];
    const float* bkh = (const float*)d_in[11];

    char* ws = (char*)d_ws;
    float* Smat  = (float*)(ws);                        // 64 MB
    float* q_low = (float*)(ws + 67108864);             // 512 KB
    float* k_low = (float*)(ws + 67633152);             // 512 KB
    float* sh    = (float*)(ws + 68157440);             // 32 KB
    float* cinv  = (float*)(ws + 68222976);             // 32 KB
    unsigned short* VthH = (unsigned short*)(ws + 68255744);  // 2 MB
    unsigned short* VthL = (unsigned short*)(ws + 70352896);  // 2 MB
    // pcol lives only until colred_final2; part (written later) overlaps it.
    float* pcol  = (float*)(ws + 72450048);             // 8 MB
    float* part  = (float*)(ws + 72450048);             // ksplit*4 MB

    const size_t part_off = 72450048;
    const size_t part_sz  = (size_t)NB * SEQ * DIM * 4;  // 4 MB
    int ksplit = 1;
    if      (ws_size >= part_off + 8 * part_sz) ksplit = 8;
    else if (ws_size >= part_off + 4 * part_sz) ksplit = 4;
    else if (ws_size >= part_off + 2 * part_sz) ksplit = 2;

    proj_kernel<<<dim3((NB * SEQ) / 16), 256, 0, stream>>>(
        queries, keys, Wql, bql, Wkl, bkl, Wqh, bqh, Wkh, bkh, q_low, k_low, sh);

    vsplit_kernel<<<dim3(SEQ / 32, DIM / 32, NB), 256, 0, stream>>>(
        values, VthH, VthL);

    score_topk8<<<dim3((NB * SEQ) / 8), 256, 0, stream>>>(
        q_low, k_low, sh, valid, Smat, pcol);

    colred_final2<<<dim3((NB * SEQ) / 256), 256, 0, stream>>>(pcol, cinv);

    if (ksplit == 1) {
        out_mfma<<<dim3(SEQ / QT, 1, NB), 256, 0, stream>>>(
            Smat, VthH, VthL, cinv, (float*)d_out, SEQ);
    } else {
        out_mfma<<<dim3(SEQ / QT, ksplit, NB), 256, 0, stream>>>(
            Smat, VthH, VthL, cinv, part, SEQ / ksplit);
        reduce_kernel<<<(NB * SEQ * DIM / 4) / 256, 256, 0, stream>>>(
            part, (float*)d_out, ksplit);
    }
}

// Round 10
// 200.207 us; speedup vs baseline: 1.2867x; 1.2867x over previous
//
#include <hip/hip_runtime.h>
#include <float.h>
#include <math.h>

#define SEQ 2048
#define NB 4
#define DIM 128
#define DL 16
#define NEGV (-1e9f)
#define TOPK 8

#define QT 128      // q-rows per out block
#define KC 64       // k chunk staged in LDS (out kernel)
#define QCH 32      // q-chunk for colred
#define KCH 128     // k_low cols staged per chunk (score kernel)

typedef unsigned long long u64;
typedef __attribute__((ext_vector_type(8))) short short8;
typedef __attribute__((ext_vector_type(4))) float f32x4;

__device__ __forceinline__ int lanes_below(u64 m) {
    return __builtin_amdgcn_mbcnt_hi((unsigned)(m >> 32),
           __builtin_amdgcn_mbcnt_lo((unsigned)m, 0));
}

__device__ __forceinline__ void top8_insert(float* s, float key) {
    #pragma unroll
    for (int i = 0; i < 8; ++i) {
        float a = s[i];
        s[i] = fmaxf(a, key);
        key  = fminf(a, key);
    }
}

__device__ __forceinline__ float top8_merge(float* s) {
    #pragma unroll
    for (int off = 1; off < 64; off <<= 1) {
        float o[8], t[8];
        #pragma unroll
        for (int i = 0; i < 8; ++i)
            o[i] = __shfl_xor(s[i], off, 64);
        #pragma unroll
        for (int i = 0; i < 8; ++i)
            t[i] = fmaxf(s[i], o[7 - i]);
        #pragma unroll
        for (int i = 0; i < 4; ++i) {
            float a = t[i], c = t[i + 4];
            t[i] = fmaxf(a, c); t[i + 4] = fminf(a, c);
        }
        #pragma unroll
        for (int g2 = 0; g2 < 8; g2 += 4) {
            float a = t[g2], c = t[g2 + 2];
            t[g2] = fmaxf(a, c); t[g2 + 2] = fminf(a, c);
            a = t[g2 + 1]; c = t[g2 + 3];
            t[g2 + 1] = fmaxf(a, c); t[g2 + 3] = fminf(a, c);
        }
        #pragma unroll
        for (int g1 = 0; g1 < 8; g1 += 2) {
            float a = t[g1], c = t[g1 + 1];
            t[g1] = fmaxf(a, c); t[g1 + 1] = fminf(a, c);
        }
        #pragma unroll
        for (int i = 0; i < 8; ++i) s[i] = t[i];
    }
    return s[7];
}

// bf16 round-to-nearest-even of f32 (returns 16-bit pattern)
__device__ __forceinline__ unsigned bf16_rne(float x) {
    unsigned u = __float_as_uint(x);
    return (u + 0x7FFFu + ((u >> 16) & 1u)) >> 16;
}

// ---------------------------------------------------------------------------
// Kernel A: q_low/k_low projections + per-key high-rank correction scalar sh.
// ---------------------------------------------------------------------------
__global__ __launch_bounds__(256) void proj_kernel(
    const float* __restrict__ q, const float* __restrict__ k,
    const float* __restrict__ Wql, const float* __restrict__ bql,
    const float* __restrict__ Wkl, const float* __restrict__ bkl,
    const float* __restrict__ Wqh, const float* __restrict__ bqh,
    const float* __restrict__ Wkh, const float* __restrict__ bkh,
    float* __restrict__ q_low, float* __restrict__ k_low,
    float* __restrict__ sh)
{
    __shared__ float Ws[4][DIM * DL];
    __shared__ float rowq[16][DIM];
    __shared__ float rowk[16][DIM];
    int tid = threadIdx.x;
    for (int i = tid; i < DIM * DL; i += 256) {
        Ws[0][i] = Wql[i];
        Ws[1][i] = Wkl[i];
        Ws[2][i] = Wqh[i];
        Ws[3][i] = Wkh[i];
    }
    int r0 = blockIdx.x * 16;
    for (int i = tid; i < 16 * DIM; i += 256) {
        int rr = i >> 7, cc = i & 127;
        rowq[rr][cc] = q[(size_t)(r0 + rr) * DIM + cc];
        rowk[rr][cc] = k[(size_t)(r0 + rr) * DIM + cc];
    }
    __syncthreads();
    int g = tid >> 4;
    int e = tid & 15;
    float aql = 0.f, akl = 0.f, aqh = 0.f, akh = 0.f;
    #pragma unroll 8
    for (int i = 0; i < DIM; ++i) {
        float qv = rowq[g][i], kv = rowk[g][i];
        aql = fmaf(qv, Ws[0][i * DL + e], aql);
        akl = fmaf(kv, Ws[1][i * DL + e], akl);
        aqh = fmaf(qv, Ws[2][i * DL + e], aqh);
        akh = fmaf(kv, Ws[3][i * DL + e], akh);
    }
    int t = r0 + g;
    q_low[(size_t)t * DL + e] = aql + bql[e];
    k_low[(size_t)t * DL + e] = akl + bkl[e];
    float qp = aqh + bqh[e];
    float kp = akh + bkh[e];
    float prod = qp * kp;
    #pragma unroll
    for (int off = 8; off >= 1; off >>= 1)
        prod += __shfl_xor(prod, off, 16);
    if (e == 0) sh[t] = 0.25f * prod;
}

// ---------------------------------------------------------------------------
// Kernel A2: V transpose + fold cinv + bf16 hi/lo split: V'[b][d][k] with
// V'[k,d] = V[k,d] * cinv[b,k].  (runs AFTER colred_final)
// ---------------------------------------------------------------------------
__global__ __launch_bounds__(256) void vsplit_kernel(
    const float* __restrict__ V, const float* __restrict__ cinv,
    unsigned short* __restrict__ VH, unsigned short* __restrict__ VL)
{
    __shared__ float T[32][33];
    int kb = blockIdx.x * 32, db = blockIdx.y * 32, b = blockIdx.z;
    int tid = threadIdx.x;
    {
        int r = tid >> 3, cg = tid & 7;
        float ci = cinv[(size_t)b * SEQ + kb + r];
        float4 v = *(const float4*)(V + ((size_t)b * SEQ + kb + r) * DIM + db + cg * 4);
        T[r][cg * 4 + 0] = v.x * ci; T[r][cg * 4 + 1] = v.y * ci;
        T[r][cg * 4 + 2] = v.z * ci; T[r][cg * 4 + 3] = v.w * ci;
    }
    __syncthreads();
    int dr = tid >> 3, kg = tid & 7;
    unsigned h[4], l[4];
    #pragma unroll
    for (int j = 0; j < 4; ++j) {
        float f = T[kg * 4 + j][dr];
        unsigned hi = bf16_rne(f);
        float hf = __uint_as_float(hi << 16);
        unsigned lo = bf16_rne(f - hf);
        h[j] = hi; l[j] = lo;
    }
    size_t o = ((size_t)b * DIM + db + dr) * SEQ + kb + kg * 4;
    *(uint2*)(VH + o) = make_uint2(h[0] | (h[1] << 16), h[2] | (h[3] << 16));
    *(uint2*)(VL + o) = make_uint2(l[0] | (l[1] << 16), l[2] | (l[3] << 16));
}

// ---------------------------------------------------------------------------
// Kernel B v9: R6's proven structure (4 waves x 2 rows, 2-buffer k_low LDS
// pipeline) with chunk = 128 cols (2 x 8 KB LDS) for occupancy: LDS no
// longer caps blocks/CU (160/16 = 10; wave slots allow 8). Pass 1: scores ->
// Smat + value-only top-8. Pass 2: patch 8 winners with sh (exact ties).
// ---------------------------------------------------------------------------
__global__ __launch_bounds__(256) void score_topk9(
    const float* __restrict__ q_low, const float* __restrict__ k_low,
    const float* __restrict__ sh, const int* __restrict__ valid_lens,
    float* __restrict__ Smat)
{
    __shared__ float KT[2][KCH * DL];   // 2 x 8 KB

    int tid  = threadIdx.x;
    int lane = tid & 63;
    int wv   = tid >> 6;
    int row0 = __builtin_amdgcn_readfirstlane(blockIdx.x * 8 + wv * 2);
    int b    = row0 >> 11;
    int qi0  = row0 & (SEQ - 1);
    int qi1  = qi0 + 1;

    float qv0[16], qv1[16];
    {
        const float* qp0 = q_low + (size_t)row0 * DL;
        #pragma unroll
        for (int e = 0; e < 16; ++e) {
            qv0[e] = qp0[e] * 0.25f;
            qv1[e] = qp0[DL + e] * 0.25f;
        }
    }

    const float4* kb4 = (const float4*)(k_low + (size_t)b * SEQ * DL);
    const int*    vlb = valid_lens + (size_t)b * SEQ;
    const float*  shb = sh + (size_t)b * SEQ;
    float* Srow0 = Smat + (size_t)row0 * SEQ;
    float* Srow1 = Srow0 + SEQ;

    float s0[8], s1[8];
    #pragma unroll
    for (int i = 0; i < 8; ++i) { s0[i] = -FLT_MAX; s1[i] = -FLT_MAX; }

    // prologue: stage chunk 0 (8 KB = 512 float4 = 2/thread)
    float4 stg[2];
    #pragma unroll
    for (int i = 0; i < 2; ++i) stg[i] = kb4[tid + i * 256];
    {
        float4* d = (float4*)KT[0];
        #pragma unroll
        for (int i = 0; i < 2; ++i) d[tid + i * 256] = stg[i];
    }
    __syncthreads();

    for (int c = 0; c < SEQ / KCH; ++c) {
        if (c < SEQ / KCH - 1) {
            #pragma unroll
            for (int i = 0; i < 2; ++i)
                stg[i] = kb4[(c + 1) * 512 + tid + i * 256];
        }
        int vli[2];
        #pragma unroll
        for (int j = 0; j < 2; ++j)
            vli[j] = vlb[c * KCH + lane + j * 64];

        const float* Kc = KT[c & 1];
        #pragma unroll
        for (int j = 0; j < 2; ++j) {
            int ccol = lane + j * 64;
            int col  = c * KCH + ccol;
            const float4* kp4 = (const float4*)(Kc + ccol * DL);
            float4 v0 = kp4[0], v1 = kp4[1], v2 = kp4[2], v3 = kp4[3];

            float a0 = 0.f, a1 = 0.f;
            a0 = fmaf(qv0[0],  v0.x, a0); a1 = fmaf(qv1[0],  v0.x, a1);
            a0 = fmaf(qv0[1],  v0.y, a0); a1 = fmaf(qv1[1],  v0.y, a1);
            a0 = fmaf(qv0[2],  v0.z, a0); a1 = fmaf(qv1[2],  v0.z, a1);
            a0 = fmaf(qv0[3],  v0.w, a0); a1 = fmaf(qv1[3],  v0.w, a1);
            a0 = fmaf(qv0[4],  v1.x, a0); a1 = fmaf(qv1[4],  v1.x, a1);
            a0 = fmaf(qv0[5],  v1.y, a0); a1 = fmaf(qv1[5],  v1.y, a1);
            a0 = fmaf(qv0[6],  v1.z, a0); a1 = fmaf(qv1[6],  v1.z, a1);
            a0 = fmaf(qv0[7],  v1.w, a0); a1 = fmaf(qv1[7],  v1.w, a1);
            a0 = fmaf(qv0[8],  v2.x, a0); a1 = fmaf(qv1[8],  v2.x, a1);
            a0 = fmaf(qv0[9],  v2.y, a0); a1 = fmaf(qv1[9],  v2.y, a1);
            a0 = fmaf(qv0[10], v2.z, a0); a1 = fmaf(qv1[10], v2.z, a1);
            a0 = fmaf(qv0[11], v2.w, a0); a1 = fmaf(qv1[11], v2.w, a1);
            a0 = fmaf(qv0[12], v3.x, a0); a1 = fmaf(qv1[12], v3.x, a1);
            a0 = fmaf(qv0[13], v3.y, a0); a1 = fmaf(qv1[13], v3.y, a1);
            a0 = fmaf(qv0[14], v3.z, a0); a1 = fmaf(qv1[14], v3.z, a1);
            a0 = fmaf(qv0[15], v3.w, a0); a1 = fmaf(qv1[15], v3.w, a1);

            int v = vli[j];
            v = v < 0 ? 0 : (v > SEQ - 1 ? SEQ - 1 : v);
            if (v == qi0) a0 += NEGV;
            if (v == qi1) a1 += NEGV;
            Srow0[col] = a0;
            Srow1[col] = a1;
            top8_insert(s0, a0);
            top8_insert(s1, a1);
        }
        if (c < SEQ / KCH - 1) {
            float4* d = (float4*)KT[(c + 1) & 1];
            #pragma unroll
            for (int i = 0; i < 2; ++i) d[tid + i * 256] = stg[i];
            __syncthreads();
        }
    }

    float t8[2];
    t8[0] = top8_merge(s0);
    t8[1] = top8_merge(s1);

    // pass 2: per row, count >= t8 and patch the 8 winners with sh
    for (int r = 0; r < 2; ++r) {
        float* Sr = r ? Srow1 : Srow0;
        float thr = t8[r];
        float sc[32];
        #pragma unroll 8
        for (int j = 0; j < 32; ++j)
            sc[j] = Sr[lane + j * 64];
        int cnt = 0;
        #pragma unroll
        for (int j = 0; j < 32; ++j) {
            cnt += (sc[j] >= thr) ? 1 : 0;
            cnt += (sc[j] >  thr) ? 65536 : 0;
        }
        #pragma unroll
        for (int off = 1; off < 64; off <<= 1)
            cnt += __shfl_xor(cnt, off, 64);
        int c_ge = cnt & 0xFFFF;
        int c_gt = cnt >> 16;

        if (c_ge == 8) {
            #pragma unroll 8
            for (int j = 0; j < 32; ++j) {
                int col = lane + j * 64;
                if (sc[j] >= thr) Sr[col] = shb[col];
            }
        } else {
            int need = 8 - c_gt;
            int total = 0;
            for (int j = 0; j < 32; ++j) {
                int col = lane + j * 64;
                bool eq = (sc[j] == thr);
                u64 bal = __ballot(eq);
                int before = total + lanes_below(bal);
                bool sel = (sc[j] > thr) || (eq && before < need);
                if (sel) Sr[col] = shb[col];
                total += (int)__popcll(bal);
            }
        }
    }
}

// ---------------------------------------------------------------------------
// Kernel C1/C2: column (q-axis) exp-sum (no max: |scores| <= ~8, masked
// entries = -1e9 -> exp = 0; <=1 masked per column so sum > 0).
// ---------------------------------------------------------------------------
__global__ __launch_bounds__(256) void colred_partial(
    const float* __restrict__ Smat, float* __restrict__ pl)
{
    int kcol = blockIdx.x * 256 + threadIdx.x;
    int qc = blockIdx.y;   // 0..63
    int b  = blockIdx.z;
    const float* Sp = Smat + (size_t)b * SEQ * SEQ + (size_t)(qc * QCH) * SEQ + kcol;
    float l = 0.f;
    #pragma unroll 4
    for (int qq = 0; qq < QCH; ++qq)
        l += __expf(Sp[(size_t)qq * SEQ]);
    pl[((size_t)b * 64 + qc) * SEQ + kcol] = l;
}

__global__ __launch_bounds__(256) void colred_final(
    const float* __restrict__ pl, float* __restrict__ cinv)
{
    int idx = blockIdx.x * 256 + threadIdx.x;
    int b = idx >> 11, kcol = idx & (SEQ - 1);
    float l = 0.f;
    #pragma unroll
    for (int c = 0; c < 64; ++c)
        l += pl[((size_t)b * 64 + c) * SEQ + kcol];
    cinv[idx] = 1.f / l;
}

// ---------------------------------------------------------------------------
// Kernel D v4: MFMA PV with cinv pre-folded into V'. Block = 128q x 128d,
// k-chunks of 64, ksplit partials. P = exp(S) A-fragments in registers
// (hi/lo bf16 split); V'^T hi/lo in XOR-swizzled LDS.
// ---------------------------------------------------------------------------
__global__ __launch_bounds__(256) void out_mfma(
    const float* __restrict__ Smat, const unsigned short* __restrict__ VH,
    const unsigned short* __restrict__ VL,
    float* __restrict__ dst, int krange)
{
    __shared__ unsigned int VtH[DIM * 32];   // 16 KB
    __shared__ unsigned int VtL[DIM * 32];   // 16 KB

    int tid  = threadIdx.x;
    int w    = tid >> 6;
    int lane = tid & 63;
    int ln   = lane & 15;
    int quad = lane >> 4;
    int q0   = blockIdx.x * QT;
    int ksid = blockIdx.y;
    int b    = blockIdx.z;
    int kbeg = ksid * krange;

    const float* Sb = Smat + (size_t)b * SEQ * SEQ;
    const unsigned short* VHb = VH + (size_t)b * DIM * SEQ;
    const unsigned short* VLb = VL + (size_t)b * DIM * SEQ;

    f32x4 acc[2][8];
    #pragma unroll
    for (int mt = 0; mt < 2; ++mt)
        #pragma unroll
        for (int nt = 0; nt < 8; ++nt)
            acc[mt][nt] = (f32x4){0.f, 0.f, 0.f, 0.f};

    int sd0   = tid >> 3;
    int skseg = tid & 7;

    for (int k0 = kbeg; k0 < kbeg + krange; k0 += KC) {
        #pragma unroll
        for (int it = 0; it < 4; ++it) {
            int d = sd0 + it * 32;
            size_t go = (size_t)d * SEQ + k0 + skseg * 8;
            uint4 hv = *(const uint4*)(VHb + go);
            uint4 lv = *(const uint4*)(VLb + go);
            int wa = d * 32 + ((skseg ^ (d & 7)) << 2);
            *(uint4*)&VtH[wa] = hv;
            *(uint4*)&VtL[wa] = lv;
        }

        short8 Ah[2][2], Al[2][2];
        #pragma unroll
        for (int ks = 0; ks < 2; ++ks) {
            int kk = k0 + ks * 32 + quad * 8;
            #pragma unroll
            for (int mt = 0; mt < 2; ++mt) {
                const float* Sp = Sb + (size_t)(q0 + w * 32 + mt * 16 + ln) * SEQ + kk;
                float4 sa = *(const float4*)Sp;
                float4 sb = *(const float4*)(Sp + 4);
                float p[8];
                p[0] = __expf(sa.x);
                p[1] = __expf(sa.y);
                p[2] = __expf(sa.z);
                p[3] = __expf(sa.w);
                p[4] = __expf(sb.x);
                p[5] = __expf(sb.y);
                p[6] = __expf(sb.z);
                p[7] = __expf(sb.w);
                #pragma unroll
                for (int j = 0; j < 8; ++j) {
                    unsigned hi = bf16_rne(p[j]);
                    float hf = __uint_as_float(hi << 16);
                    unsigned lo = bf16_rne(p[j] - hf);
                    Ah[mt][ks][j] = (short)hi;
                    Al[mt][ks][j] = (short)lo;
                }
            }
        }
        __syncthreads();

        #pragma unroll
        for (int nt = 0; nt < 8; ++nt) {
            int d = nt * 16 + ln;
            #pragma unroll
            for (int ks = 0; ks < 2; ++ks) {
                int kseg = ks * 4 + quad;
                int wa = d * 32 + ((kseg ^ (d & 7)) << 2);
                short8 bh = *(short8*)&VtH[wa];
                short8 bl = *(short8*)&VtL[wa];
                #pragma unroll
                for (int mt = 0; mt < 2; ++mt) {
                    acc[mt][nt] = __builtin_amdgcn_mfma_f32_16x16x32_bf16(
                        Ah[mt][ks], bh, acc[mt][nt], 0, 0, 0);
                    acc[mt][nt] = __builtin_amdgcn_mfma_f32_16x16x32_bf16(
                        Al[mt][ks], bh, acc[mt][nt], 0, 0, 0);
                    acc[mt][nt] = __builtin_amdgcn_mfma_f32_16x16x32_bf16(
                        Ah[mt][ks], bl, acc[mt][nt], 0, 0, 0);
                }
            }
        }
        __syncthreads();
    }

    float* dp = dst + (size_t)ksid * ((size_t)NB * SEQ * DIM)
                    + (size_t)b * SEQ * DIM;
    #pragma unroll
    for (int mt = 0; mt < 2; ++mt) {
        #pragma unroll
        for (int r = 0; r < 4; ++r) {
            float* o = dp + (size_t)(q0 + w * 32 + mt * 16 + quad * 4 + r) * DIM + ln;
            #pragma unroll
            for (int nt = 0; nt < 8; ++nt)
                o[nt * 16] = acc[mt][nt][r];
        }
    }
}

__global__ __launch_bounds__(256) void reduce_kernel(
    const float* __restrict__ part, float* __restrict__ out, int ksplit)
{
    int idx = blockIdx.x * 256 + threadIdx.x;
    const float4* p = (const float4*)part;
    float4 a = p[idx];
    for (int s = 1; s < ksplit; ++s) {
        float4 q = p[(size_t)idx + (size_t)s * 262144];
        a.x += q.x; a.y += q.y; a.z += q.z; a.w += q.w;
    }
    ((float4*)out)[idx] = a;
}

extern "C" void kernel_launch(void* const* d_in, const int* in_sizes, int n_in,
                              void* d_out, int out_size, void* d_ws, size_t ws_size,
                              hipStream_t stream)
{
    const float* queries = (const float*)d_in[0];
    const float* keys    = (const float*)d_in[1];
    const float* values  = (const float*)d_in[2];
    const int*   valid   = (const int*)d_in[3];
    const float* Wql = (const float*)d_in[4];
    const float* bql = (const float*)d_in[5];
    const float* Wkl = (const float*)d_in[6];
    const float* bkl = (const float*)d_in[7];
    const float* Wqh = (const float*)d_in[8];
    const float* bqh = (const float*)d_in[9];
    const float* Wkh = (const float*)d_in[10];
    const float* bkh = (const float*)d_in[11];

    char* ws = (char*)d_ws;
    float* Smat  = (float*)(ws);                        // 64 MB
    float* q_low = (float*)(ws + 67108864);             // 512 KB
    float* k_low = (float*)(ws + 67633152);             // 512 KB
    float* sh    = (float*)(ws + 68157440);             // 32 KB
    float* cinv  = (float*)(ws + 68222976);             // 32 KB
    unsigned short* VthH = (unsigned short*)(ws + 68255744);  // 2 MB
    unsigned short* VthL = (unsigned short*)(ws + 70352896);  // 2 MB
    // pl lives only until colred_final; part (written later) overlaps it.
    float* pl    = (float*)(ws + 72450048);             // 2 MB
    float* part  = (float*)(ws + 72450048);             // ksplit*4 MB

    const size_t part_off = 72450048;
    const size_t part_sz  = (size_t)NB * SEQ * DIM * 4;  // 4 MB
    int ksplit = 1;
    if      (ws_size >= part_off + 8 * part_sz) ksplit = 8;
    else if (ws_size >= part_off + 4 * part_sz) ksplit = 4;
    else if (ws_size >= part_off + 2 * part_sz) ksplit = 2;

    proj_kernel<<<dim3((NB * SEQ) / 16), 256, 0, stream>>>(
        queries, keys, Wql, bql, Wkl, bkl, Wqh, bqh, Wkh, bkh, q_low, k_low, sh);

    score_topk9<<<dim3((NB * SEQ) / 8), 256, 0, stream>>>(
        q_low, k_low, sh, valid, Smat);

    colred_partial<<<dim3(SEQ / 256, SEQ / QCH, NB), 256, 0, stream>>>(Smat, pl);

    colred_final<<<dim3((NB * SEQ) / 256), 256, 0, stream>>>(pl, cinv);

    vsplit_kernel<<<dim3(SEQ / 32, DIM / 32, NB), 256, 0, stream>>>(
        values, cinv, VthH, VthL);

    if (ksplit == 1) {
        out_mfma<<<dim3(SEQ / QT, 1, NB), 256, 0, stream>>>(
            Smat, VthH, VthL, (float*)d_out, SEQ);
    } else {
        out_mfma<<<dim3(SEQ / QT, ksplit, NB), 256, 0, stream>>>(
            Smat, VthH, VthL, part, SEQ / ksplit);
        reduce_kernel<<<(NB * SEQ * DIM / 4) / 256, 256, 0, stream>>>(
            part, (float*)d_out, ksplit);
    }
}

// Round 11
// 196.934 us; speedup vs baseline: 1.3081x; 1.0166x over previous
//
#include <hip/hip_runtime.h>
#include <float.h>
#include <math.h>

#define SEQ 2048
#define NB 4
#define DIM 128
#define DL 16
#define NEGV (-1e9f)
#define TOPK 8

#define QT 128      // q-rows per out block
#define KC 64       // k chunk staged in LDS (out kernel)
#define QCH 32      // q-chunk for colred
#define KCH 128     // k_low cols staged per chunk (score kernel)
#define KSTR 20     // col stride in words: 20*i mod 32 covers all banks, 16B-aligned

typedef unsigned long long u64;
typedef __attribute__((ext_vector_type(8))) short short8;
typedef __attribute__((ext_vector_type(4))) float f32x4;

__device__ __forceinline__ int lanes_below(u64 m) {
    return __builtin_amdgcn_mbcnt_hi((unsigned)(m >> 32),
           __builtin_amdgcn_mbcnt_lo((unsigned)m, 0));
}

__device__ __forceinline__ void top8_insert(float* s, float key) {
    #pragma unroll
    for (int i = 0; i < 8; ++i) {
        float a = s[i];
        s[i] = fmaxf(a, key);
        key  = fminf(a, key);
    }
}

__device__ __forceinline__ float top8_merge(float* s) {
    #pragma unroll
    for (int off = 1; off < 64; off <<= 1) {
        float o[8], t[8];
        #pragma unroll
        for (int i = 0; i < 8; ++i)
            o[i] = __shfl_xor(s[i], off, 64);
        #pragma unroll
        for (int i = 0; i < 8; ++i)
            t[i] = fmaxf(s[i], o[7 - i]);
        #pragma unroll
        for (int i = 0; i < 4; ++i) {
            float a = t[i], c = t[i + 4];
            t[i] = fmaxf(a, c); t[i + 4] = fminf(a, c);
        }
        #pragma unroll
        for (int g2 = 0; g2 < 8; g2 += 4) {
            float a = t[g2], c = t[g2 + 2];
            t[g2] = fmaxf(a, c); t[g2 + 2] = fminf(a, c);
            a = t[g2 + 1]; c = t[g2 + 3];
            t[g2 + 1] = fmaxf(a, c); t[g2 + 3] = fminf(a, c);
        }
        #pragma unroll
        for (int g1 = 0; g1 < 8; g1 += 2) {
            float a = t[g1], c = t[g1 + 1];
            t[g1] = fmaxf(a, c); t[g1 + 1] = fminf(a, c);
        }
        #pragma unroll
        for (int i = 0; i < 8; ++i) s[i] = t[i];
    }
    return s[7];
}

// bf16 round-to-nearest-even of f32 (returns 16-bit pattern)
__device__ __forceinline__ unsigned bf16_rne(float x) {
    unsigned u = __float_as_uint(x);
    return (u + 0x7FFFu + ((u >> 16) & 1u)) >> 16;
}

// ---------------------------------------------------------------------------
// Kernel A: q_low/k_low projections + per-key high-rank correction scalar sh.
// ---------------------------------------------------------------------------
__global__ __launch_bounds__(256) void proj_kernel(
    const float* __restrict__ q, const float* __restrict__ k,
    const float* __restrict__ Wql, const float* __restrict__ bql,
    const float* __restrict__ Wkl, const float* __restrict__ bkl,
    const float* __restrict__ Wqh, const float* __restrict__ bqh,
    const float* __restrict__ Wkh, const float* __restrict__ bkh,
    float* __restrict__ q_low, float* __restrict__ k_low,
    float* __restrict__ sh)
{
    __shared__ float Ws[4][DIM * DL];
    __shared__ float rowq[16][DIM];
    __shared__ float rowk[16][DIM];
    int tid = threadIdx.x;
    for (int i = tid; i < DIM * DL; i += 256) {
        Ws[0][i] = Wql[i];
        Ws[1][i] = Wkl[i];
        Ws[2][i] = Wqh[i];
        Ws[3][i] = Wkh[i];
    }
    int r0 = blockIdx.x * 16;
    for (int i = tid; i < 16 * DIM; i += 256) {
        int rr = i >> 7, cc = i & 127;
        rowq[rr][cc] = q[(size_t)(r0 + rr) * DIM + cc];
        rowk[rr][cc] = k[(size_t)(r0 + rr) * DIM + cc];
    }
    __syncthreads();
    int g = tid >> 4;
    int e = tid & 15;
    float aql = 0.f, akl = 0.f, aqh = 0.f, akh = 0.f;
    #pragma unroll 8
    for (int i = 0; i < DIM; ++i) {
        float qv = rowq[g][i], kv = rowk[g][i];
        aql = fmaf(qv, Ws[0][i * DL + e], aql);
        akl = fmaf(kv, Ws[1][i * DL + e], akl);
        aqh = fmaf(qv, Ws[2][i * DL + e], aqh);
        akh = fmaf(kv, Ws[3][i * DL + e], akh);
    }
    int t = r0 + g;
    q_low[(size_t)t * DL + e] = aql + bql[e];
    k_low[(size_t)t * DL + e] = akl + bkl[e];
    float qp = aqh + bqh[e];
    float kp = akh + bkh[e];
    float prod = qp * kp;
    #pragma unroll
    for (int off = 8; off >= 1; off >>= 1)
        prod += __shfl_xor(prod, off, 16);
    if (e == 0) sh[t] = 0.25f * prod;
}

// ---------------------------------------------------------------------------
// Kernel A2: V transpose + fold cinv + bf16 hi/lo split: V'[b][d][k] with
// V'[k,d] = V[k,d] * cinv[b,k].  (runs AFTER colred_final)
// ---------------------------------------------------------------------------
__global__ __launch_bounds__(256) void vsplit_kernel(
    const float* __restrict__ V, const float* __restrict__ cinv,
    unsigned short* __restrict__ VH, unsigned short* __restrict__ VL)
{
    __shared__ float T[32][33];
    int kb = blockIdx.x * 32, db = blockIdx.y * 32, b = blockIdx.z;
    int tid = threadIdx.x;
    {
        int r = tid >> 3, cg = tid & 7;
        float ci = cinv[(size_t)b * SEQ + kb + r];
        float4 v = *(const float4*)(V + ((size_t)b * SEQ + kb + r) * DIM + db + cg * 4);
        T[r][cg * 4 + 0] = v.x * ci; T[r][cg * 4 + 1] = v.y * ci;
        T[r][cg * 4 + 2] = v.z * ci; T[r][cg * 4 + 3] = v.w * ci;
    }
    __syncthreads();
    int dr = tid >> 3, kg = tid & 7;
    unsigned h[4], l[4];
    #pragma unroll
    for (int j = 0; j < 4; ++j) {
        float f = T[kg * 4 + j][dr];
        unsigned hi = bf16_rne(f);
        float hf = __uint_as_float(hi << 16);
        unsigned lo = bf16_rne(f - hf);
        h[j] = hi; l[j] = lo;
    }
    size_t o = ((size_t)b * DIM + db + dr) * SEQ + kb + kg * 4;
    *(uint2*)(VH + o) = make_uint2(h[0] | (h[1] << 16), h[2] | (h[3] << 16));
    *(uint2*)(VL + o) = make_uint2(l[0] | (l[1] << 16), l[2] | (l[3] << 16));
}

// ---------------------------------------------------------------------------
// Kernel B v10: R10 structure (4 waves x 2 rows, 2-buffer 128-col chunks)
// with col stride 20 words: 20*i mod 32 has period 8 covering all 32 banks,
// so both staging writes and 4x b128 column reads hit each bank exactly
// 8x/wave access (conflict floor). LDS = 2 x 10 KB.
// ---------------------------------------------------------------------------
__global__ __launch_bounds__(256) void score_topk10(
    const float* __restrict__ q_low, const float* __restrict__ k_low,
    const float* __restrict__ sh, const int* __restrict__ valid_lens,
    float* __restrict__ Smat)
{
    __shared__ float KT[2][KCH * KSTR];   // 2 x 10 KB

    int tid  = threadIdx.x;
    int lane = tid & 63;
    int wv   = tid >> 6;
    int row0 = __builtin_amdgcn_readfirstlane(blockIdx.x * 8 + wv * 2);
    int b    = row0 >> 11;
    int qi0  = row0 & (SEQ - 1);
    int qi1  = qi0 + 1;

    float qv0[16], qv1[16];
    {
        const float* qp0 = q_low + (size_t)row0 * DL;
        #pragma unroll
        for (int e = 0; e < 16; ++e) {
            qv0[e] = qp0[e] * 0.25f;
            qv1[e] = qp0[DL + e] * 0.25f;
        }
    }

    const float4* kb4 = (const float4*)(k_low + (size_t)b * SEQ * DL);
    const int*    vlb = valid_lens + (size_t)b * SEQ;
    const float*  shb = sh + (size_t)b * SEQ;
    float* Srow0 = Smat + (size_t)row0 * SEQ;
    float* Srow1 = Srow0 + SEQ;

    float s0[8], s1[8];
    #pragma unroll
    for (int i = 0; i < 8; ++i) { s0[i] = -FLT_MAX; s1[i] = -FLT_MAX; }

    // prologue: stage chunk 0 (512 float4 = 2/thread), col*KSTR + seg*4
    float4 stg[2];
    #pragma unroll
    for (int i = 0; i < 2; ++i) stg[i] = kb4[tid + i * 256];
    #pragma unroll
    for (int i = 0; i < 2; ++i) {
        int idx = tid + i * 256;
        *(float4*)&KT[0][(idx >> 2) * KSTR + (idx & 3) * 4] = stg[i];
    }
    __syncthreads();

    for (int c = 0; c < SEQ / KCH; ++c) {
        if (c < SEQ / KCH - 1) {
            #pragma unroll
            for (int i = 0; i < 2; ++i)
                stg[i] = kb4[(c + 1) * 512 + tid + i * 256];
        }
        int vli[2];
        #pragma unroll
        for (int j = 0; j < 2; ++j)
            vli[j] = vlb[c * KCH + lane + j * 64];

        const float* Kc = KT[c & 1];
        #pragma unroll
        for (int j = 0; j < 2; ++j) {
            int ccol = lane + j * 64;
            int col  = c * KCH + ccol;
            const float4* kp4 = (const float4*)(Kc + ccol * KSTR);
            float4 v0 = kp4[0], v1 = kp4[1], v2 = kp4[2], v3 = kp4[3];

            float a0 = 0.f, a1 = 0.f;
            a0 = fmaf(qv0[0],  v0.x, a0); a1 = fmaf(qv1[0],  v0.x, a1);
            a0 = fmaf(qv0[1],  v0.y, a0); a1 = fmaf(qv1[1],  v0.y, a1);
            a0 = fmaf(qv0[2],  v0.z, a0); a1 = fmaf(qv1[2],  v0.z, a1);
            a0 = fmaf(qv0[3],  v0.w, a0); a1 = fmaf(qv1[3],  v0.w, a1);
            a0 = fmaf(qv0[4],  v1.x, a0); a1 = fmaf(qv1[4],  v1.x, a1);
            a0 = fmaf(qv0[5],  v1.y, a0); a1 = fmaf(qv1[5],  v1.y, a1);
            a0 = fmaf(qv0[6],  v1.z, a0); a1 = fmaf(qv1[6],  v1.z, a1);
            a0 = fmaf(qv0[7],  v1.w, a0); a1 = fmaf(qv1[7],  v1.w, a1);
            a0 = fmaf(qv0[8],  v2.x, a0); a1 = fmaf(qv1[8],  v2.x, a1);
            a0 = fmaf(qv0[9],  v2.y, a0); a1 = fmaf(qv1[9],  v2.y, a1);
            a0 = fmaf(qv0[10], v2.z, a0); a1 = fmaf(qv1[10], v2.z, a1);
            a0 = fmaf(qv0[11], v2.w, a0); a1 = fmaf(qv1[11], v2.w, a1);
            a0 = fmaf(qv0[12], v3.x, a0); a1 = fmaf(qv1[12], v3.x, a1);
            a0 = fmaf(qv0[13], v3.y, a0); a1 = fmaf(qv1[13], v3.y, a1);
            a0 = fmaf(qv0[14], v3.z, a0); a1 = fmaf(qv1[14], v3.z, a1);
            a0 = fmaf(qv0[15], v3.w, a0); a1 = fmaf(qv1[15], v3.w, a1);

            int v = vli[j];
            v = v < 0 ? 0 : (v > SEQ - 1 ? SEQ - 1 : v);
            if (v == qi0) a0 += NEGV;
            if (v == qi1) a1 += NEGV;
            Srow0[col] = a0;
            Srow1[col] = a1;
            top8_insert(s0, a0);
            top8_insert(s1, a1);
        }
        if (c < SEQ / KCH - 1) {
            float* d = KT[(c + 1) & 1];
            #pragma unroll
            for (int i = 0; i < 2; ++i) {
                int idx = tid + i * 256;
                *(float4*)&d[(idx >> 2) * KSTR + (idx & 3) * 4] = stg[i];
            }
            __syncthreads();
        }
    }

    float t8[2];
    t8[0] = top8_merge(s0);
    t8[1] = top8_merge(s1);

    // pass 2: per row, count >= t8 and patch the 8 winners with sh
    for (int r = 0; r < 2; ++r) {
        float* Sr = r ? Srow1 : Srow0;
        float thr = t8[r];
        float sc[32];
        #pragma unroll 8
        for (int j = 0; j < 32; ++j)
            sc[j] = Sr[lane + j * 64];
        int cnt = 0;
        #pragma unroll
        for (int j = 0; j < 32; ++j) {
            cnt += (sc[j] >= thr) ? 1 : 0;
            cnt += (sc[j] >  thr) ? 65536 : 0;
        }
        #pragma unroll
        for (int off = 1; off < 64; off <<= 1)
            cnt += __shfl_xor(cnt, off, 64);
        int c_ge = cnt & 0xFFFF;
        int c_gt = cnt >> 16;

        if (c_ge == 8) {
            #pragma unroll 8
            for (int j = 0; j < 32; ++j) {
                int col = lane + j * 64;
                if (sc[j] >= thr) Sr[col] = shb[col];
            }
        } else {
            int need = 8 - c_gt;
            int total = 0;
            for (int j = 0; j < 32; ++j) {
                int col = lane + j * 64;
                bool eq = (sc[j] == thr);
                u64 bal = __ballot(eq);
                int before = total + lanes_below(bal);
                bool sel = (sc[j] > thr) || (eq && before < need);
                if (sel) Sr[col] = shb[col];
                total += (int)__popcll(bal);
            }
        }
    }
}

// ---------------------------------------------------------------------------
// Kernel C1/C2: column (q-axis) exp-sum (no max: |scores| <= ~8, masked
// entries = -1e9 -> exp = 0; <=1 masked per column so sum > 0).
// ---------------------------------------------------------------------------
__global__ __launch_bounds__(256) void colred_partial(
    const float* __restrict__ Smat, float* __restrict__ pl)
{
    int kcol = blockIdx.x * 256 + threadIdx.x;
    int qc = blockIdx.y;   // 0..63
    int b  = blockIdx.z;
    const float* Sp = Smat + (size_t)b * SEQ * SEQ + (size_t)(qc * QCH) * SEQ + kcol;
    float l = 0.f;
    #pragma unroll 4
    for (int qq = 0; qq < QCH; ++qq)
        l += __expf(Sp[(size_t)qq * SEQ]);
    pl[((size_t)b * 64 + qc) * SEQ + kcol] = l;
}

__global__ __launch_bounds__(256) void colred_final(
    const float* __restrict__ pl, float* __restrict__ cinv)
{
    int idx = blockIdx.x * 256 + threadIdx.x;
    int b = idx >> 11, kcol = idx & (SEQ - 1);
    float l = 0.f;
    #pragma unroll
    for (int c = 0; c < 64; ++c)
        l += pl[((size_t)b * 64 + c) * SEQ + kcol];
    cinv[idx] = 1.f / l;
}

// ---------------------------------------------------------------------------
// Kernel D v4: MFMA PV with cinv pre-folded into V'. Block = 128q x 128d,
// k-chunks of 64, ksplit partials. P = exp(S) A-fragments in registers
// (hi/lo bf16 split); V'^T hi/lo in XOR-swizzled LDS.
// ---------------------------------------------------------------------------
__global__ __launch_bounds__(256) void out_mfma(
    const float* __restrict__ Smat, const unsigned short* __restrict__ VH,
    const unsigned short* __restrict__ VL,
    float* __restrict__ dst, int krange)
{
    __shared__ unsigned int VtH[DIM * 32];   // 16 KB
    __shared__ unsigned int VtL[DIM * 32];   // 16 KB

    int tid  = threadIdx.x;
    int w    = tid >> 6;
    int lane = tid & 63;
    int ln   = lane & 15;
    int quad = lane >> 4;
    int q0   = blockIdx.x * QT;
    int ksid = blockIdx.y;
    int b    = blockIdx.z;
    int kbeg = ksid * krange;

    const float* Sb = Smat + (size_t)b * SEQ * SEQ;
    const unsigned short* VHb = VH + (size_t)b * DIM * SEQ;
    const unsigned short* VLb = VL + (size_t)b * DIM * SEQ;

    f32x4 acc[2][8];
    #pragma unroll
    for (int mt = 0; mt < 2; ++mt)
        #pragma unroll
        for (int nt = 0; nt < 8; ++nt)
            acc[mt][nt] = (f32x4){0.f, 0.f, 0.f, 0.f};

    int sd0   = tid >> 3;
    int skseg = tid & 7;

    for (int k0 = kbeg; k0 < kbeg + krange; k0 += KC) {
        #pragma unroll
        for (int it = 0; it < 4; ++it) {
            int d = sd0 + it * 32;
            size_t go = (size_t)d * SEQ + k0 + skseg * 8;
            uint4 hv = *(const uint4*)(VHb + go);
            uint4 lv = *(const uint4*)(VLb + go);
            int wa = d * 32 + ((skseg ^ (d & 7)) << 2);
            *(uint4*)&VtH[wa] = hv;
            *(uint4*)&VtL[wa] = lv;
        }

        short8 Ah[2][2], Al[2][2];
        #pragma unroll
        for (int ks = 0; ks < 2; ++ks) {
            int kk = k0 + ks * 32 + quad * 8;
            #pragma unroll
            for (int mt = 0; mt < 2; ++mt) {
                const float* Sp = Sb + (size_t)(q0 + w * 32 + mt * 16 + ln) * SEQ + kk;
                float4 sa = *(const float4*)Sp;
                float4 sb = *(const float4*)(Sp + 4);
                float p[8];
                p[0] = __expf(sa.x);
                p[1] = __expf(sa.y);
                p[2] = __expf(sa.z);
                p[3] = __expf(sa.w);
                p[4] = __expf(sb.x);
                p[5] = __expf(sb.y);
                p[6] = __expf(sb.z);
                p[7] = __expf(sb.w);
                #pragma unroll
                for (int j = 0; j < 8; ++j) {
                    unsigned hi = bf16_rne(p[j]);
                    float hf = __uint_as_float(hi << 16);
                    unsigned lo = bf16_rne(p[j] - hf);
                    Ah[mt][ks][j] = (short)hi;
                    Al[mt][ks][j] = (short)lo;
                }
            }
        }
        __syncthreads();

        #pragma unroll
        for (int nt = 0; nt < 8; ++nt) {
            int d = nt * 16 + ln;
            #pragma unroll
            for (int ks = 0; ks < 2; ++ks) {
                int kseg = ks * 4 + quad;
                int wa = d * 32 + ((kseg ^ (d & 7)) << 2);
                short8 bh = *(short8*)&VtH[wa];
                short8 bl = *(short8*)&VtL[wa];
                #pragma unroll
                for (int mt = 0; mt < 2; ++mt) {
                    acc[mt][nt] = __builtin_amdgcn_mfma_f32_16x16x32_bf16(
                        Ah[mt][ks], bh, acc[mt][nt], 0, 0, 0);
                    acc[mt][nt] = __builtin_amdgcn_mfma_f32_16x16x32_bf16(
                        Al[mt][ks], bh, acc[mt][nt], 0, 0, 0);
                    acc[mt][nt] = __builtin_amdgcn_mfma_f32_16x16x32_bf16(
                        Ah[mt][ks], bl, acc[mt][nt], 0, 0, 0);
                }
            }
        }
        __syncthreads();
    }

    float* dp = dst + (size_t)ksid * ((size_t)NB * SEQ * DIM)
                    + (size_t)b * SEQ * DIM;
    #pragma unroll
    for (int mt = 0; mt < 2; ++mt) {
        #pragma unroll
        for (int r = 0; r < 4; ++r) {
            float* o = dp + (size_t)(q0 + w * 32 + mt * 16 + quad * 4 + r) * DIM + ln;
            #pragma unroll
            for (int nt = 0; nt < 8; ++nt)
                o[nt * 16] = acc[mt][nt][r];
        }
    }
}

__global__ __launch_bounds__(256) void reduce_kernel(
    const float* __restrict__ part, float* __restrict__ out, int ksplit)
{
    int idx = blockIdx.x * 256 + threadIdx.x;
    const float4* p = (const float4*)part;
    float4 a = p[idx];
    for (int s = 1; s < ksplit; ++s) {
        float4 q = p[(size_t)idx + (size_t)s * 262144];
        a.x += q.x; a.y += q.y; a.z += q.z; a.w += q.w;
    }
    ((float4*)out)[idx] = a;
}

extern "C" void kernel_launch(void* const* d_in, const int* in_sizes, int n_in,
                              void* d_out, int out_size, void* d_ws, size_t ws_size,
                              hipStream_t stream)
{
    const float* queries = (const float*)d_in[0];
    const float* keys    = (const float*)d_in[1];
    const float* values  = (const float*)d_in[2];
    const int*   valid   = (const int*)d_in[3];
    const float* Wql = (const float*)d_in[4];
    const float* bql = (const float*)d_in[5];
    const float* Wkl = (const float*)d_in[6];
    const float* bkl = (const float*)d_in[7];
    const float* Wqh = (const float*)d_in[8];
    const float* bqh = (const float*)d_in[9];
    const float* Wkh = (const float*)d_in[10];
    const float* bkh = (const float*)d_in[11];

    char* ws = (char*)d_ws;
    float* Smat  = (float*)(ws);                        // 64 MB
    float* q_low = (float*)(ws + 67108864);             // 512 KB
    float* k_low = (float*)(ws + 67633152);             // 512 KB
    float* sh    = (float*)(ws + 68157440);             // 32 KB
    float* cinv  = (float*)(ws + 68222976);             // 32 KB
    unsigned short* VthH = (unsigned short*)(ws + 68255744);  // 2 MB
    unsigned short* VthL = (unsigned short*)(ws + 70352896);  // 2 MB
    // pl lives only until colred_final; part (written later) overlaps it.
    float* pl    = (float*)(ws + 72450048);             // 2 MB
    float* part  = (float*)(ws + 72450048);             // ksplit*4 MB

    const size_t part_off = 72450048;
    const size_t part_sz  = (size_t)NB * SEQ * DIM * 4;  // 4 MB
    int ksplit = 1;
    if      (ws_size >= part_off + 8 * part_sz) ksplit = 8;
    else if (ws_size >= part_off + 4 * part_sz) ksplit = 4;
    else if (ws_size >= part_off + 2 * part_sz) ksplit = 2;

    proj_kernel<<<dim3((NB * SEQ) / 16), 256, 0, stream>>>(
        queries, keys, Wql, bql, Wkl, bkl, Wqh, bqh, Wkh, bkh, q_low, k_low, sh);

    score_topk10<<<dim3((NB * SEQ) / 8), 256, 0, stream>>>(
        q_low, k_low, sh, valid, Smat);

    colred_partial<<<dim3(SEQ / 256, SEQ / QCH, NB), 256, 0, stream>>>(Smat, pl);

    colred_final<<<dim3((NB * SEQ) / 256), 256, 0, stream>>>(pl, cinv);

    vsplit_kernel<<<dim3(SEQ / 32, DIM / 32, NB), 256, 0, stream>>>(
        values, cinv, VthH, VthL);

    if (ksplit == 1) {
        out_mfma<<<dim3(SEQ / QT, 1, NB), 256, 0, stream>>>(
            Smat, VthH, VthL, (float*)d_out, SEQ);
    } else {
        out_mfma<<<dim3(SEQ / QT, ksplit, NB), 256, 0, stream>>>(
            Smat, VthH, VthL, part, SEQ / ksplit);
        reduce_kernel<<<(NB * SEQ * DIM / 4) / 256, 256, 0, stream>>>(
            part, (float*)d_out, ksplit);
    }
}